// Round 8
// baseline (146.626 us; speedup 1.0000x reference)
//
#include <hip/hip_runtime.h>

#define INP (128*128*64)   // 1048576
#define NB 8
#define NBLK1 4096         // spatial blocks: INP / 256

typedef __attribute__((ext_vector_type(4))) float f32x4;
typedef int v4i __attribute__((ext_vector_type(4)));

#define DYB 256
#define DZB 32768

#if __has_builtin(__builtin_amdgcn_make_buffer_rsrc) && __has_builtin(__builtin_amdgcn_raw_buffer_load_b32)
#define RSRC_T __amdgpu_buffer_rsrc_t
__device__ __forceinline__ RSRC_T make_rsrc(const float* p) {
    return __builtin_amdgcn_make_buffer_rsrc((void*)p, (short)0, INP * 4, 0x00020000);
}
__device__ __forceinline__ float bload(RSRC_T r, int boff) {
    return __builtin_bit_cast(float, __builtin_amdgcn_raw_buffer_load_b32(r, boff, 0, 0));
}
#else
#define RSRC_T v4i
__device__ __forceinline__ RSRC_T make_rsrc(const float* p) {
    union { const float* p; unsigned u[2]; } pun; pun.p = p;
    RSRC_T r;
    r.x = (int)pun.u[0]; r.y = (int)pun.u[1]; r.z = INP * 4; r.w = 0x00020000;
    return r;
}
__device__ __forceinline__ float bload(RSRC_T r, int boff) {
    return __builtin_amdgcn_raw_buffer_load_f32(r, boff, 0, 0);
}
#endif

__device__ __forceinline__ float wave_reduce(float v) {
    #pragma unroll
    for (int off = 32; off > 0; off >>= 1) v += __shfl_down(v, off, 64);
    return v;
}

// CLAMPED prep (R4/R5/R6-proven semantics). All offsets in-bounds by
// construction; zeroed axis weights implement zeros-padding. Do NOT use
// unclamped offsets with SRSRC: compiler imm-folding of (negative voffset
// + imm) breaks the >=33-bit bounds check (R3/R7 failures, absmax 0.128).
struct Prep {
    int o[8];
    float wx0, wx1, wy0, wy1, wz0, wz1;
};

__device__ __forceinline__ Prep do_prep(const float* __restrict__ t,
                                        float xs, float ys, float zs) {
    float ix = fmaf(t[0], xs, fmaf(t[1], ys, fmaf(t[2],  zs, t[3])));
    float iy = fmaf(t[4], xs, fmaf(t[5], ys, fmaf(t[6],  zs, t[7])));
    float iz = fmaf(t[8], xs, fmaf(t[9], ys, fmaf(t[10], zs, t[11])));
    ix = fmaf(ix, 32.f, 31.5f);
    iy = fmaf(iy, 64.f, 63.5f);
    iz = fmaf(iz, 64.f, 63.5f);

    const float fx = floorf(ix), fy = floorf(iy), fz = floorf(iz);
    const int x0 = (int)fx, y0 = (int)fy, z0 = (int)fz;
    const int x1 = x0 + 1,  y1 = y0 + 1,  z1 = z0 + 1;

    Prep p;
    p.wx1 = ix - fx; p.wx0 = 1.f - p.wx1;
    p.wy1 = iy - fy; p.wy0 = 1.f - p.wy1;
    p.wz1 = iz - fz; p.wz0 = 1.f - p.wz1;
    p.wx0 = ((unsigned)x0 < 64u)  ? p.wx0 : 0.f;
    p.wx1 = ((unsigned)x1 < 64u)  ? p.wx1 : 0.f;
    p.wy0 = ((unsigned)y0 < 128u) ? p.wy0 : 0.f;
    p.wy1 = ((unsigned)y1 < 128u) ? p.wy1 : 0.f;
    p.wz0 = ((unsigned)z0 < 128u) ? p.wz0 : 0.f;
    p.wz1 = ((unsigned)z1 < 128u) ? p.wz1 : 0.f;

    const int xc0 = min(max(x0, 0), 63),  xc1 = min(max(x1, 0), 63);
    const int yc0 = min(max(y0, 0), 127), yc1 = min(max(y1, 0), 127);
    const int zc0 = min(max(z0, 0), 127), zc1 = min(max(z1, 0), 127);
    const int rb00 = ((zc0 << 7) + yc0) << 8;
    const int rb01 = ((zc0 << 7) + yc1) << 8;
    const int rb10 = ((zc1 << 7) + yc0) << 8;
    const int rb11 = ((zc1 << 7) + yc1) << 8;
    const int xb0 = xc0 << 2, xb1 = xc1 << 2;
    p.o[0] = rb00 + xb0; p.o[1] = rb00 + xb1;
    p.o[2] = rb01 + xb0; p.o[3] = rb01 + xb1;
    p.o[4] = rb10 + xb0; p.o[5] = rb10 + xb1;
    p.o[6] = rb11 + xb0; p.o[7] = rb11 + xb1;
    return p;
}

__device__ __forceinline__ float gather_blend(RSRC_T r, const Prep& p) {
    const float v000 = bload(r, p.o[0]);
    const float v001 = bload(r, p.o[1]);
    const float v010 = bload(r, p.o[2]);
    const float v011 = bload(r, p.o[3]);
    const float v100 = bload(r, p.o[4]);
    const float v101 = bload(r, p.o[5]);
    const float v110 = bload(r, p.o[6]);
    const float v111 = bload(r, p.o[7]);
    const float bx00 = fmaf(p.wx1, v001, p.wx0 * v000);
    const float bx01 = fmaf(p.wx1, v011, p.wx0 * v010);
    const float bx10 = fmaf(p.wx1, v101, p.wx0 * v100);
    const float bx11 = fmaf(p.wx1, v111, p.wx0 * v110);
    const float by0  = fmaf(p.wy1, bx01, p.wy0 * bx00);
    const float by1  = fmaf(p.wy1, bx11, p.wy0 * bx10);
    return fmaf(p.wz1, by1, p.wz0 * by0);
}

// ---------------------------------------------------------------------------
// K1 production (R5-exact): one thread = one (batch, voxel) sample.
// ---------------------------------------------------------------------------
__global__ __launch_bounds__(256) void k_sample(
    const float* __restrict__ x, const int* __restrict__ r_index,
    const float* __restrict__ theta, const float* __restrict__ lnw,
    float* __restrict__ x_reg, float* __restrict__ partial)
{
    const int b = blockIdx.y;
    const int i = blockIdx.x * 256 + threadIdx.x;
    const int w = i & 63, h = (i >> 6) & 127, d = i >> 13;

    const float xs = fmaf((float)w, 1.f/32.f, 1.f/64.f  - 1.f);
    const float ys = fmaf((float)h, 1.f/64.f, 1.f/128.f - 1.f);
    const float zs = fmaf((float)d, 1.f/64.f, 1.f/128.f - 1.f);

    const Prep p = do_prep(theta + r_index[b] * 12, xs, ys, zs);
    const RSRC_T r = make_rsrc(x + (size_t)b * INP);
    const float out = gather_blend(r, p);

    __builtin_nontemporal_store(out, x_reg + (size_t)b * INP + i);

    float acc = wave_reduce(out * lnw[i]);
    __shared__ float sm[4];
    const int lane = threadIdx.x & 63;
    const int wv   = threadIdx.x >> 6;
    if (lane == 0) sm[wv] = acc;
    __syncthreads();
    if (threadIdx.x == 0)
        partial[b * NBLK1 + blockIdx.x] = sm[0] + sm[1] + sm[2] + sm[3];
}

// ---------------------------------------------------------------------------
// Diagnostics — FULL scale (grid NBLK1 x NB) so they appear in top-5.
// All write wave-partials into the diag region (DCE-proof), no d_out access.
// ---------------------------------------------------------------------------
// A: full sampling path minus x_reg store / lnw / LDS tail.
__global__ __launch_bounds__(256) void k_diag_full(
    const float* __restrict__ x, const int* __restrict__ r_index,
    const float* __restrict__ theta, float* __restrict__ diag)
{
    const int b = blockIdx.y;
    const int i = blockIdx.x * 256 + threadIdx.x;
    const int w = i & 63, h = (i >> 6) & 127, d = i >> 13;
    const float xs = fmaf((float)w, 1.f/32.f, 1.f/64.f  - 1.f);
    const float ys = fmaf((float)h, 1.f/64.f, 1.f/128.f - 1.f);
    const float zs = fmaf((float)d, 1.f/64.f, 1.f/128.f - 1.f);
    const Prep p = do_prep(theta + r_index[b] * 12, xs, ys, zs);
    const RSRC_T r = make_rsrc(x + (size_t)b * INP);
    const float out = wave_reduce(gather_blend(r, p));
    if ((threadIdx.x & 63) == 0)
        diag[(size_t)(b * NBLK1 + blockIdx.x) * 4 + (threadIdx.x >> 6)] = out;
}

// B: same 8-gather instruction count, contiguous in-bounds addresses.
__global__ __launch_bounds__(256) void k_diag_stream(
    const float* __restrict__ x, float* __restrict__ diag)
{
    const int b = blockIdx.y;
    const int i = blockIdx.x * 256 + threadIdx.x;
    const int base = (i & (INP/2 - 1)) << 2;   // +DZB+DYB+4 stays in bounds
    const RSRC_T r = make_rsrc(x + (size_t)b * INP);
    float s = bload(r, base)             + bload(r, base + 4)
            + bload(r, base + DYB)       + bload(r, base + DYB + 4)
            + bload(r, base + DZB)       + bload(r, base + DZB + 4)
            + bload(r, base + DZB + DYB) + bload(r, base + DZB + DYB + 4);
    s = wave_reduce(s);
    if ((threadIdx.x & 63) == 0)
        diag[(size_t)(b * NBLK1 + blockIdx.x) * 4 + (threadIdx.x >> 6)] = s;
}

// C: prep VALU only, x4 repeats (calibrates VALU rate; 1x ~ value/4).
__global__ __launch_bounds__(256) void k_diag_prep(
    const int* __restrict__ r_index, const float* __restrict__ theta,
    float* __restrict__ diag)
{
    const int b = blockIdx.y;
    const float* t = theta + r_index[b] * 12;
    float val = 0.f;
    #pragma unroll
    for (int it = 0; it < 4; ++it) {
        const int i = (blockIdx.x * 256 + threadIdx.x) + it * 1337;
        const int w = i & 63, h = (i >> 6) & 127, d = (i >> 13) & 127;
        const float xs = fmaf((float)w, 1.f/32.f, 1.f/64.f  - 1.f);
        const float ys = fmaf((float)h, 1.f/64.f, 1.f/128.f - 1.f);
        const float zs = fmaf((float)d, 1.f/64.f, 1.f/128.f - 1.f);
        const Prep p = do_prep(t, xs, ys, zs);
        int osum = 0;
        #pragma unroll
        for (int j = 0; j < 8; ++j) osum += p.o[j];
        val += p.wx0 + p.wx1 + p.wy0 + p.wy1 + p.wz0 + p.wz1
             + (float)osum * 1e-30f;
    }
    val = wave_reduce(val);
    if ((threadIdx.x & 63) == 0)
        diag[(size_t)(b * NBLK1 + blockIdx.x) * 4 + (threadIdx.x >> 6)] = val;
}

// ---------------------------------------------------------------------------
__global__ __launch_bounds__(256) void k_reduce(
    const float* __restrict__ partial, float* __restrict__ s)
{
    const int b = blockIdx.x;
    float v = 0.f;
    for (int t = threadIdx.x; t < NBLK1; t += 256) v += partial[b * NBLK1 + t];
    __shared__ float sm[4];
    v = wave_reduce(v);
    if ((threadIdx.x & 63) == 0) sm[threadIdx.x >> 6] = v;
    __syncthreads();
    if (threadIdx.x == 0) s[b] = sm[0] + sm[1] + sm[2] + sm[3];
}

__global__ __launch_bounds__(256) void k_outer(
    const float* __restrict__ lnw, const float* __restrict__ s,
    float* __restrict__ L)
{
    const int i = blockIdx.x * 256 + threadIdx.x;
    const f32x4 w4 = ((const f32x4*)lnw)[i];
    #pragma unroll
    for (int b = 0; b < NB; ++b) {
        const float sb = s[b];
        f32x4 o = sb * w4;
        __builtin_nontemporal_store(o, (f32x4*)(L + (size_t)b * INP) + i);
    }
}

extern "C" void kernel_launch(void* const* d_in, const int* in_sizes, int n_in,
                              void* d_out, int out_size, void* d_ws, size_t ws_size,
                              hipStream_t stream) {
    const float* x       = (const float*)d_in[0];
    const int*   r_index = (const int*)d_in[1];
    const float* theta   = (const float*)d_in[2];
    const float* lnw     = (const float*)d_in[3];

    float* x_reg = (float*)d_out;
    float* L     = (float*)d_out + (size_t)NB * INP;

    // ws layout: [0,512KB) diag (overlaps partial; partial dead before diags)
    //            [512KB, +32B) s
    float* partial = (float*)d_ws;                    // 8*4096 floats (128 KB)
    float* diag    = (float*)d_ws;                    // 131072 floats (512 KB)
    float* s       = (float*)((char*)d_ws + (512 << 10));

    dim3 grid1(NBLK1, NB);
    k_sample<<<grid1, 256, 0, stream>>>(x, r_index, theta, lnw, x_reg, partial);
    k_reduce<<<NB, 256, 0, stream>>>(partial, s);
    k_outer<<<INP / 4 / 256, 256, 0, stream>>>(lnw, s, L);
    // diagnostics after partial is consumed; they only touch ws
    k_diag_full  <<<grid1, 256, 0, stream>>>(x, r_index, theta, diag);
    k_diag_stream<<<grid1, 256, 0, stream>>>(x, diag);
    k_diag_prep  <<<grid1, 256, 0, stream>>>(r_index, theta, diag);
}

// Round 9
// 78.998 us; speedup vs baseline: 1.8561x; 1.8561x over previous
//
#include <hip/hip_runtime.h>

#define INP (128*128*64)   // 1048576
#define NB 8
#define NQ  (INP/4)        // 262144 quad-threads per batch
#define NBLKQ 1024         // k_sample blocks per batch (NQ/256)
#define NPART 4096         // wave partials per batch = NBLKQ*4

typedef __attribute__((ext_vector_type(4))) float f32x4;
typedef int v4i __attribute__((ext_vector_type(4)));

#if __has_builtin(__builtin_amdgcn_make_buffer_rsrc) && __has_builtin(__builtin_amdgcn_raw_buffer_load_b32)
#define RSRC_T __amdgpu_buffer_rsrc_t
__device__ __forceinline__ RSRC_T make_rsrc(const float* p) {
    return __builtin_amdgcn_make_buffer_rsrc((void*)p, (short)0, INP * 4, 0x00020000);
}
__device__ __forceinline__ float bload(RSRC_T r, int boff) {
    return __builtin_bit_cast(float, __builtin_amdgcn_raw_buffer_load_b32(r, boff, 0, 0));
}
#else
#define RSRC_T v4i
__device__ __forceinline__ RSRC_T make_rsrc(const float* p) {
    union { const float* p; unsigned u[2]; } pun; pun.p = p;
    RSRC_T r;
    r.x = (int)pun.u[0]; r.y = (int)pun.u[1]; r.z = INP * 4; r.w = 0x00020000;
    return r;
}
__device__ __forceinline__ float bload(RSRC_T r, int boff) {
    return __builtin_amdgcn_raw_buffer_load_f32(r, boff, 0, 0);
}
#endif

__device__ __forceinline__ float wave_reduce(float v) {
    #pragma unroll
    for (int off = 32; off > 0; off >>= 1) v += __shfl_down(v, off, 64);
    return v;
}

// One-voxel trilinear sample at voxel-space coords (ix,iy,iz).
// PROVEN semantics (R4/R5/R6): clamped always-in-bounds offsets + zeroed
// axis weights. Do NOT use unclamped offsets with SRSRC (R3/R7: imm-folding
// of negative voffset breaks the >=33-bit bounds check).
__device__ __forceinline__ float sample1(RSRC_T r, float ix, float iy, float iz) {
    const float fx = floorf(ix), fy = floorf(iy), fz = floorf(iz);
    const int x0 = (int)fx, y0 = (int)fy, z0 = (int)fz;
    const int x1 = x0 + 1,  y1 = y0 + 1,  z1 = z0 + 1;

    float wx1 = ix - fx, wx0 = 1.f - wx1;
    float wy1 = iy - fy, wy0 = 1.f - wy1;
    float wz1 = iz - fz, wz0 = 1.f - wz1;
    wx0 = ((unsigned)x0 < 64u)  ? wx0 : 0.f;
    wx1 = ((unsigned)x1 < 64u)  ? wx1 : 0.f;
    wy0 = ((unsigned)y0 < 128u) ? wy0 : 0.f;
    wy1 = ((unsigned)y1 < 128u) ? wy1 : 0.f;
    wz0 = ((unsigned)z0 < 128u) ? wz0 : 0.f;
    wz1 = ((unsigned)z1 < 128u) ? wz1 : 0.f;

    const int xc0 = min(max(x0, 0), 63),  xc1 = min(max(x1, 0), 63);
    const int yc0 = min(max(y0, 0), 127), yc1 = min(max(y1, 0), 127);
    const int zc0 = min(max(z0, 0), 127), zc1 = min(max(z1, 0), 127);
    const int zs0 = zc0 << 15, zs1 = zc1 << 15;    // byte strides: z=32768
    const int ys0 = yc0 << 8,  ys1 = yc1 << 8;     //               y=256
    const int xb0 = xc0 << 2,  xb1 = xc1 << 2;
    const int rb00 = zs0 + ys0, rb01 = zs0 + ys1;
    const int rb10 = zs1 + ys0, rb11 = zs1 + ys1;

    const float v000 = bload(r, rb00 + xb0);
    const float v001 = bload(r, rb00 + xb1);
    const float v010 = bload(r, rb01 + xb0);
    const float v011 = bload(r, rb01 + xb1);
    const float v100 = bload(r, rb10 + xb0);
    const float v101 = bload(r, rb10 + xb1);
    const float v110 = bload(r, rb11 + xb0);
    const float v111 = bload(r, rb11 + xb1);

    const float bx00 = fmaf(wx1, v001, wx0 * v000);
    const float bx01 = fmaf(wx1, v011, wx0 * v010);
    const float bx10 = fmaf(wx1, v101, wx0 * v100);
    const float bx11 = fmaf(wx1, v111, wx0 * v110);
    const float by0  = fmaf(wy1, bx01, wy0 * bx00);
    const float by1  = fmaf(wy1, bx11, wy0 * bx10);
    return fmaf(wz1, by1, wz0 * by0);
}

// ---------------------------------------------------------------------------
// K1: one thread = 4 consecutive x-voxels of one batch. The affine matvec is
// computed once; per-voxel coords advance by constants (normalize/unnorm
// factors cancel: d(ix)/dw = t0, d(iy)/dw = 2*t4, d(iz)/dw = 2*t8).
// f32x4 NT store of x_reg, f32x4 lnw load, wave-level dot partials.
// ---------------------------------------------------------------------------
__global__ __launch_bounds__(256) void k_sample(
    const float* __restrict__ x, const int* __restrict__ r_index,
    const float* __restrict__ theta, const float* __restrict__ lnw,
    float* __restrict__ x_reg, float* __restrict__ partial)
{
    const int b  = blockIdx.y;
    const int i4 = blockIdx.x * 256 + threadIdx.x;   // quad index
    const int wq = (i4 & 15) << 2;                   // w of voxel 0 (0..60)
    const int h  = (i4 >> 4) & 127;
    const int d  = i4 >> 11;

    const f32x4 w4 = ((const f32x4*)lnw)[i4];        // issue early

    // normalized coords of voxel 0, align_corners=False
    const float xs = fmaf((float)wq, 1.f/32.f, 1.f/64.f  - 1.f);
    const float ys = fmaf((float)h,  1.f/64.f, 1.f/128.f - 1.f);
    const float zs = fmaf((float)d,  1.f/64.f, 1.f/128.f - 1.f);

    const float* __restrict__ t = theta + r_index[b] * 12;   // uniform
    float gx = fmaf(t[0], xs, fmaf(t[1], ys, fmaf(t[2],  zs, t[3])));
    float gy = fmaf(t[4], xs, fmaf(t[5], ys, fmaf(t[6],  zs, t[7])));
    float gz = fmaf(t[8], xs, fmaf(t[9], ys, fmaf(t[10], zs, t[11])));
    const float ix0 = fmaf(gx, 32.f, 31.5f);   // voxel-space coords, k=0
    const float iy0 = fmaf(gy, 64.f, 63.5f);
    const float iz0 = fmaf(gz, 64.f, 63.5f);
    const float sx = t[0];                     // per-w-step in voxel units
    const float sy = 2.f * t[4];
    const float sz = 2.f * t[8];

    const RSRC_T r = make_rsrc(x + (size_t)b * INP);

    const float o0 = sample1(r, ix0, iy0, iz0);
    const float o1 = sample1(r, ix0 + sx, iy0 + sy, iz0 + sz);
    const float o2 = sample1(r, fmaf(2.f, sx, ix0), fmaf(2.f, sy, iy0), fmaf(2.f, sz, iz0));
    const float o3 = sample1(r, fmaf(3.f, sx, ix0), fmaf(3.f, sy, iy0), fmaf(3.f, sz, iz0));

    f32x4 o; o.x = o0; o.y = o1; o.z = o2; o.w = o3;
    __builtin_nontemporal_store(o, (f32x4*)(x_reg + (size_t)b * INP) + i4);

    // per-thread dot contribution, then wave-level deterministic reduction
    float acc = o0 * w4.x;
    acc = fmaf(o1, w4.y, acc);
    acc = fmaf(o2, w4.z, acc);
    acc = fmaf(o3, w4.w, acc);
    acc = wave_reduce(acc);
    if ((threadIdx.x & 63) == 0)
        partial[(size_t)b * NPART + blockIdx.x * 4 + (threadIdx.x >> 6)] = acc;
}

// ---------------------------------------------------------------------------
// K2: reduce (8, NPART) partials -> s[8]
// ---------------------------------------------------------------------------
__global__ __launch_bounds__(256) void k_reduce(
    const float* __restrict__ partial, float* __restrict__ s)
{
    const int b = blockIdx.x;
    float v = 0.f;
    for (int t = threadIdx.x; t < NPART; t += 256)
        v += partial[(size_t)b * NPART + t];
    __shared__ float sm[4];
    v = wave_reduce(v);
    if ((threadIdx.x & 63) == 0) sm[threadIdx.x >> 6] = v;
    __syncthreads();
    if (threadIdx.x == 0) s[b] = sm[0] + sm[1] + sm[2] + sm[3];
}

// ---------------------------------------------------------------------------
// K3: L[b,i] = s[b] * lnw[i], f32x4, NT stores
// ---------------------------------------------------------------------------
__global__ __launch_bounds__(256) void k_outer(
    const float* __restrict__ lnw, const float* __restrict__ s,
    float* __restrict__ L)
{
    const int i = blockIdx.x * 256 + threadIdx.x;
    const f32x4 w4 = ((const f32x4*)lnw)[i];
    #pragma unroll
    for (int b = 0; b < NB; ++b) {
        const float sb = s[b];
        f32x4 o = sb * w4;
        __builtin_nontemporal_store(o, (f32x4*)(L + (size_t)b * INP) + i);
    }
}

extern "C" void kernel_launch(void* const* d_in, const int* in_sizes, int n_in,
                              void* d_out, int out_size, void* d_ws, size_t ws_size,
                              hipStream_t stream) {
    const float* x       = (const float*)d_in[0];
    const int*   r_index = (const int*)d_in[1];
    const float* theta   = (const float*)d_in[2];
    const float* lnw     = (const float*)d_in[3];

    float* x_reg = (float*)d_out;
    float* L     = (float*)d_out + (size_t)NB * INP;

    float* partial = (float*)d_ws;            // 8*4096 floats = 128 KB
    float* s       = partial + NB * NPART;    // 8 floats

    dim3 grid1(NBLKQ, NB);
    k_sample<<<grid1, 256, 0, stream>>>(x, r_index, theta, lnw, x_reg, partial);
    k_reduce<<<NB, 256, 0, stream>>>(partial, s);
    k_outer<<<INP / 4 / 256, 256, 0, stream>>>(lnw, s, L);
}

// Round 10
// 54.287 us; speedup vs baseline: 2.7009x; 1.4552x over previous
//
#include <hip/hip_runtime.h>

#define INP (128*128*64)   // 1048576
#define NB 8
#define NBLK1 4096         // spatial blocks: INP / 256
#define NPART (NBLK1 * 4)  // wave-level partials per batch

typedef __attribute__((ext_vector_type(4))) float f32x4;
typedef __attribute__((ext_vector_type(2))) float f32x2;
typedef int v4i __attribute__((ext_vector_type(4)));

#if __has_builtin(__builtin_amdgcn_make_buffer_rsrc) && __has_builtin(__builtin_amdgcn_raw_buffer_load_b32)
#define RSRC_T __amdgpu_buffer_rsrc_t
__device__ __forceinline__ RSRC_T make_rsrc(const float* p) {
    return __builtin_amdgcn_make_buffer_rsrc((void*)p, (short)0, INP * 4, 0x00020000);
}
__device__ __forceinline__ float bload(RSRC_T r, int boff) {
    return __builtin_bit_cast(float, __builtin_amdgcn_raw_buffer_load_b32(r, boff, 0, 0));
}
#else
#define RSRC_T v4i
__device__ __forceinline__ RSRC_T make_rsrc(const float* p) {
    union { const float* p; unsigned u[2]; } pun; pun.p = p;
    RSRC_T r;
    r.x = (int)pun.u[0]; r.y = (int)pun.u[1]; r.z = INP * 4; r.w = 0x00020000;
    return r;
}
__device__ __forceinline__ float bload(RSRC_T r, int boff) {
    return __builtin_amdgcn_raw_buffer_load_f32(r, boff, 0, 0);
}
#endif

#if __has_builtin(__builtin_amdgcn_raw_buffer_load_b64)
__device__ __forceinline__ f32x2 bload2(RSRC_T r, int boff) {
    return __builtin_bit_cast(f32x2, __builtin_amdgcn_raw_buffer_load_b64(r, boff, 0, 0));
}
#else
__device__ __forceinline__ f32x2 bload2(RSRC_T r, int boff) {
    f32x2 v; v.x = bload(r, boff); v.y = bload(r, boff + 4); return v;
}
#endif

__device__ __forceinline__ float wave_reduce(float v) {
    #pragma unroll
    for (int off = 32; off > 0; off >>= 1) v += __shfl_down(v, off, 64);
    return v;
}

// ---------------------------------------------------------------------------
// K1: one thread = one (batch, voxel) sample (R5/R6 proven TLP structure),
// but each (z,y) row's two x-corners come from ONE 8-byte buffer load at
// xp = clamp(x0,0,62) (row-aligned, always in-bounds), with edge cases
// resolved by 2 shared compares + cndmask:
//   v000 = (x0>=63) ? pair.y : pair.x   (x0=63: wx1=0, need x[63]=pair.y)
//   v001 = (x0<0)   ? pair.x : pair.y   (x0=-1: wx0=0, need x[0]=pair.x)
// All other OOB cases have both wx zeroed. Gather instrs per sample: 8 -> 4.
// ---------------------------------------------------------------------------
__global__ __launch_bounds__(256) void k_sample(
    const float* __restrict__ x, const int* __restrict__ r_index,
    const float* __restrict__ theta, const float* __restrict__ lnw,
    float* __restrict__ x_reg, float* __restrict__ partial)
{
    const int b = blockIdx.y;
    const int i = blockIdx.x * 256 + threadIdx.x;
    const int w = i & 63, h = (i >> 6) & 127, d = i >> 13;

    const float wt = lnw[i];   // independent, issue early

    const float xs = fmaf((float)w, 1.f/32.f, 1.f/64.f  - 1.f);
    const float ys = fmaf((float)h, 1.f/64.f, 1.f/128.f - 1.f);
    const float zs = fmaf((float)d, 1.f/64.f, 1.f/128.f - 1.f);

    const float* __restrict__ t = theta + r_index[b] * 12;   // uniform
    float ix = fmaf(t[0], xs, fmaf(t[1], ys, fmaf(t[2],  zs, t[3])));
    float iy = fmaf(t[4], xs, fmaf(t[5], ys, fmaf(t[6],  zs, t[7])));
    float iz = fmaf(t[8], xs, fmaf(t[9], ys, fmaf(t[10], zs, t[11])));
    ix = fmaf(ix, 32.f, 31.5f);
    iy = fmaf(iy, 64.f, 63.5f);
    iz = fmaf(iz, 64.f, 63.5f);

    const float fx = floorf(ix), fy = floorf(iy), fz = floorf(iz);
    const int x0 = (int)fx, y0 = (int)fy, z0 = (int)fz;
    const int x1 = x0 + 1,  y1 = y0 + 1,  z1 = z0 + 1;

    float wx1 = ix - fx, wx0 = 1.f - wx1;
    float wy1 = iy - fy, wy0 = 1.f - wy1;
    float wz1 = iz - fz, wz0 = 1.f - wz1;
    // zeros-padding: zero the axis weight of any out-of-range plane
    wx0 = ((unsigned)x0 < 64u)  ? wx0 : 0.f;
    wx1 = ((unsigned)x1 < 64u)  ? wx1 : 0.f;
    wy0 = ((unsigned)y0 < 128u) ? wy0 : 0.f;
    wy1 = ((unsigned)y1 < 128u) ? wy1 : 0.f;
    wz0 = ((unsigned)z0 < 128u) ? wz0 : 0.f;
    wz1 = ((unsigned)z1 < 128u) ? wz1 : 0.f;

    // clamped row bases (always in-bounds); pair base xp in [0,62]
    const int yc0 = min(max(y0, 0), 127), yc1 = min(max(y1, 0), 127);
    const int zc0 = min(max(z0, 0), 127), zc1 = min(max(z1, 0), 127);
    const int xp  = min(max(x0, 0), 62);
    const int rb00 = (((zc0 << 7) + yc0) << 8) + (xp << 2);
    const int rb01 = (((zc0 << 7) + yc1) << 8) + (xp << 2);
    const int rb10 = (((zc1 << 7) + yc0) << 8) + (xp << 2);
    const int rb11 = (((zc1 << 7) + yc1) << 8) + (xp << 2);

    const RSRC_T r = make_rsrc(x + (size_t)b * INP);
    const f32x2 p00 = bload2(r, rb00);
    const f32x2 p01 = bload2(r, rb01);
    const f32x2 p10 = bload2(r, rb10);
    const f32x2 p11 = bload2(r, rb11);

    const bool hi = (x0 >= 63);   // v*00 needs pair.y (only when x0==63)
    const bool lo = (x0 < 0);     // v*01 needs pair.x (only when x0==-1)
    const float v000 = hi ? p00.y : p00.x, v001 = lo ? p00.x : p00.y;
    const float v010 = hi ? p01.y : p01.x, v011 = lo ? p01.x : p01.y;
    const float v100 = hi ? p10.y : p10.x, v101 = lo ? p10.x : p10.y;
    const float v110 = hi ? p11.y : p11.x, v111 = lo ? p11.x : p11.y;

    const float bx00 = fmaf(wx1, v001, wx0 * v000);
    const float bx01 = fmaf(wx1, v011, wx0 * v010);
    const float bx10 = fmaf(wx1, v101, wx0 * v100);
    const float bx11 = fmaf(wx1, v111, wx0 * v110);
    const float by0  = fmaf(wy1, bx01, wy0 * bx00);
    const float by1  = fmaf(wy1, bx11, wy0 * bx10);
    const float out  = fmaf(wz1, by1, wz0 * by0);

    __builtin_nontemporal_store(out, x_reg + (size_t)b * INP + i);

    // wave-level deterministic reduction (no barrier, no LDS — R6-proven)
    const float acc = wave_reduce(out * wt);
    if ((threadIdx.x & 63) == 0)
        partial[(size_t)b * NPART + blockIdx.x * 4 + (threadIdx.x >> 6)] = acc;
}

// ---------------------------------------------------------------------------
// K2: reduce (8, NPART) partials -> s[8]
// ---------------------------------------------------------------------------
__global__ __launch_bounds__(256) void k_reduce(
    const float* __restrict__ partial, float* __restrict__ s)
{
    const int b = blockIdx.x;
    float v = 0.f;
    for (int t = threadIdx.x; t < NPART; t += 256)
        v += partial[(size_t)b * NPART + t];
    __shared__ float sm[4];
    v = wave_reduce(v);
    if ((threadIdx.x & 63) == 0) sm[threadIdx.x >> 6] = v;
    __syncthreads();
    if (threadIdx.x == 0) s[b] = sm[0] + sm[1] + sm[2] + sm[3];
}

// ---------------------------------------------------------------------------
// K3: L[b,i] = s[b] * lnw[i], f32x4, NT stores
// ---------------------------------------------------------------------------
__global__ __launch_bounds__(256) void k_outer(
    const float* __restrict__ lnw, const float* __restrict__ s,
    float* __restrict__ L)
{
    const int i = blockIdx.x * 256 + threadIdx.x;
    const f32x4 w4 = ((const f32x4*)lnw)[i];
    #pragma unroll
    for (int b = 0; b < NB; ++b) {
        const float sb = s[b];
        f32x4 o = sb * w4;
        __builtin_nontemporal_store(o, (f32x4*)(L + (size_t)b * INP) + i);
    }
}

extern "C" void kernel_launch(void* const* d_in, const int* in_sizes, int n_in,
                              void* d_out, int out_size, void* d_ws, size_t ws_size,
                              hipStream_t stream) {
    const float* x       = (const float*)d_in[0];
    const int*   r_index = (const int*)d_in[1];
    const float* theta   = (const float*)d_in[2];
    const float* lnw     = (const float*)d_in[3];

    float* x_reg = (float*)d_out;
    float* L     = (float*)d_out + (size_t)NB * INP;

    float* partial = (float*)d_ws;            // 8*16384 floats = 512 KB
    float* s       = partial + NB * NPART;    // 8 floats

    dim3 grid1(NBLK1, NB);
    k_sample<<<grid1, 256, 0, stream>>>(x, r_index, theta, lnw, x_reg, partial);
    k_reduce<<<NB, 256, 0, stream>>>(partial, s);
    k_outer<<<INP / 4 / 256, 256, 0, stream>>>(lnw, s, L);
}

// Round 11
// 44.074 us; speedup vs baseline: 3.3268x; 1.2317x over previous
//
#include <hip/hip_runtime.h>

#define INP (128*128*64)   // 1048576
#define NB 8
#define NBLK1 4096         // spatial blocks: INP / 256

typedef __attribute__((ext_vector_type(4))) float f32x4;
typedef __attribute__((ext_vector_type(2))) float f32x2;
typedef int v4i __attribute__((ext_vector_type(4)));

#if __has_builtin(__builtin_amdgcn_make_buffer_rsrc) && __has_builtin(__builtin_amdgcn_raw_buffer_load_b32)
#define RSRC_T __amdgpu_buffer_rsrc_t
__device__ __forceinline__ RSRC_T make_rsrc(const float* p) {
    return __builtin_amdgcn_make_buffer_rsrc((void*)p, (short)0, INP * 4, 0x00020000);
}
__device__ __forceinline__ float bload(RSRC_T r, int boff) {
    return __builtin_bit_cast(float, __builtin_amdgcn_raw_buffer_load_b32(r, boff, 0, 0));
}
#else
#define RSRC_T v4i
__device__ __forceinline__ RSRC_T make_rsrc(const float* p) {
    union { const float* p; unsigned u[2]; } pun; pun.p = p;
    RSRC_T r;
    r.x = (int)pun.u[0]; r.y = (int)pun.u[1]; r.z = INP * 4; r.w = 0x00020000;
    return r;
}
__device__ __forceinline__ float bload(RSRC_T r, int boff) {
    return __builtin_amdgcn_raw_buffer_load_f32(r, boff, 0, 0);
}
#endif

#if __has_builtin(__builtin_amdgcn_raw_buffer_load_b64)
__device__ __forceinline__ f32x2 bload2(RSRC_T r, int boff) {
    return __builtin_bit_cast(f32x2, __builtin_amdgcn_raw_buffer_load_b64(r, boff, 0, 0));
}
#else
__device__ __forceinline__ f32x2 bload2(RSRC_T r, int boff) {
    f32x2 v; v.x = bload(r, boff); v.y = bload(r, boff + 4); return v;
}
#endif

__device__ __forceinline__ float wave_reduce(float v) {
    #pragma unroll
    for (int off = 32; off > 0; off >>= 1) v += __shfl_down(v, off, 64);
    return v;
}

// ---------------------------------------------------------------------------
// K1: one thread = one (batch, voxel) sample. R10-proven gather: each (z,y)
// row's two x-corners via ONE 8-byte load at xp=clamp(x0,0,62) (row-aligned,
// always in-bounds), edges via 2 shared compares + cndmask:
//   v*00 = (x0>=63) ? pair.y : pair.x   (x0=63: wx1=0, need x[63]=pair.y)
//   v*01 = (x0<0)   ? pair.x : pair.y   (x0=-1: wx0=0, need x[0]=pair.x)
// All other OOB: both wx zeroed. 4 VMEM instrs/sample.
// Tail: R5-proven LDS combine -> ONE partial store per block (the R6/R10
// wave-scattered partial stores cost ~10 us of cross-XCD line ping outside
// k_sample's own duration).
// ---------------------------------------------------------------------------
__global__ __launch_bounds__(256) void k_sample(
    const float* __restrict__ x, const int* __restrict__ r_index,
    const float* __restrict__ theta, const float* __restrict__ lnw,
    float* __restrict__ x_reg, float* __restrict__ partial)
{
    const int b = blockIdx.y;
    const int i = blockIdx.x * 256 + threadIdx.x;
    const int w = i & 63, h = (i >> 6) & 127, d = i >> 13;

    const float wt = lnw[i];   // independent, issue early

    const float xs = fmaf((float)w, 1.f/32.f, 1.f/64.f  - 1.f);
    const float ys = fmaf((float)h, 1.f/64.f, 1.f/128.f - 1.f);
    const float zs = fmaf((float)d, 1.f/64.f, 1.f/128.f - 1.f);

    const float* __restrict__ t = theta + r_index[b] * 12;   // uniform
    float ix = fmaf(t[0], xs, fmaf(t[1], ys, fmaf(t[2],  zs, t[3])));
    float iy = fmaf(t[4], xs, fmaf(t[5], ys, fmaf(t[6],  zs, t[7])));
    float iz = fmaf(t[8], xs, fmaf(t[9], ys, fmaf(t[10], zs, t[11])));
    ix = fmaf(ix, 32.f, 31.5f);
    iy = fmaf(iy, 64.f, 63.5f);
    iz = fmaf(iz, 64.f, 63.5f);

    const float fx = floorf(ix), fy = floorf(iy), fz = floorf(iz);
    const int x0 = (int)fx, y0 = (int)fy, z0 = (int)fz;
    const int x1 = x0 + 1,  y1 = y0 + 1,  z1 = z0 + 1;

    float wx1 = ix - fx, wx0 = 1.f - wx1;
    float wy1 = iy - fy, wy0 = 1.f - wy1;
    float wz1 = iz - fz, wz0 = 1.f - wz1;
    // zeros-padding: zero the axis weight of any out-of-range plane
    wx0 = ((unsigned)x0 < 64u)  ? wx0 : 0.f;
    wx1 = ((unsigned)x1 < 64u)  ? wx1 : 0.f;
    wy0 = ((unsigned)y0 < 128u) ? wy0 : 0.f;
    wy1 = ((unsigned)y1 < 128u) ? wy1 : 0.f;
    wz0 = ((unsigned)z0 < 128u) ? wz0 : 0.f;
    wz1 = ((unsigned)z1 < 128u) ? wz1 : 0.f;

    // clamped row bases (always in-bounds); pair base xp in [0,62]
    const int yc0 = min(max(y0, 0), 127), yc1 = min(max(y1, 0), 127);
    const int zc0 = min(max(z0, 0), 127), zc1 = min(max(z1, 0), 127);
    const int xp  = min(max(x0, 0), 62);
    const int xpb = xp << 2;
    const int yb0 = (yc0 << 8) + xpb, yb1 = (yc1 << 8) + xpb;
    const int zb0 = zc0 << 15,        zb1 = zc1 << 15;

    const RSRC_T r = make_rsrc(x + (size_t)b * INP);
    const f32x2 p00 = bload2(r, zb0 + yb0);
    const f32x2 p01 = bload2(r, zb0 + yb1);
    const f32x2 p10 = bload2(r, zb1 + yb0);
    const f32x2 p11 = bload2(r, zb1 + yb1);

    const bool hi = (x0 >= 63);   // v*00 needs pair.y (only when x0==63)
    const bool lo = (x0 < 0);     // v*01 needs pair.x (only when x0==-1)
    const float v000 = hi ? p00.y : p00.x, v001 = lo ? p00.x : p00.y;
    const float v010 = hi ? p01.y : p01.x, v011 = lo ? p01.x : p01.y;
    const float v100 = hi ? p10.y : p10.x, v101 = lo ? p10.x : p10.y;
    const float v110 = hi ? p11.y : p11.x, v111 = lo ? p11.x : p11.y;

    const float bx00 = fmaf(wx1, v001, wx0 * v000);
    const float bx01 = fmaf(wx1, v011, wx0 * v010);
    const float bx10 = fmaf(wx1, v101, wx0 * v100);
    const float bx11 = fmaf(wx1, v111, wx0 * v110);
    const float by0  = fmaf(wy1, bx01, wy0 * bx00);
    const float by1  = fmaf(wy1, bx11, wy0 * bx10);
    const float out  = fmaf(wz1, by1, wz0 * by0);

    __builtin_nontemporal_store(out, x_reg + (size_t)b * INP + i);

    // R5-proven tail: wave shfl reduce -> LDS combine -> ONE store per block
    float acc = wave_reduce(out * wt);
    __shared__ float sm[4];
    const int lane = threadIdx.x & 63;
    const int wv   = threadIdx.x >> 6;
    if (lane == 0) sm[wv] = acc;
    __syncthreads();
    if (threadIdx.x == 0)
        partial[b * NBLK1 + blockIdx.x] = sm[0] + sm[1] + sm[2] + sm[3];
}

// ---------------------------------------------------------------------------
// K2: reduce (8, NBLK1) partials -> s[8]
// ---------------------------------------------------------------------------
__global__ __launch_bounds__(256) void k_reduce(
    const float* __restrict__ partial, float* __restrict__ s)
{
    const int b = blockIdx.x;
    float v = 0.f;
    for (int t = threadIdx.x; t < NBLK1; t += 256) v += partial[b * NBLK1 + t];
    __shared__ float sm[4];
    v = wave_reduce(v);
    if ((threadIdx.x & 63) == 0) sm[threadIdx.x >> 6] = v;
    __syncthreads();
    if (threadIdx.x == 0) s[b] = sm[0] + sm[1] + sm[2] + sm[3];
}

// ---------------------------------------------------------------------------
// K3: L[b,i] = s[b] * lnw[i], f32x4, NT stores
// ---------------------------------------------------------------------------
__global__ __launch_bounds__(256) void k_outer(
    const float* __restrict__ lnw, const float* __restrict__ s,
    float* __restrict__ L)
{
    const int i = blockIdx.x * 256 + threadIdx.x;
    const f32x4 w4 = ((const f32x4*)lnw)[i];
    #pragma unroll
    for (int b = 0; b < NB; ++b) {
        const float sb = s[b];
        f32x4 o = sb * w4;
        __builtin_nontemporal_store(o, (f32x4*)(L + (size_t)b * INP) + i);
    }
}

extern "C" void kernel_launch(void* const* d_in, const int* in_sizes, int n_in,
                              void* d_out, int out_size, void* d_ws, size_t ws_size,
                              hipStream_t stream) {
    const float* x       = (const float*)d_in[0];
    const int*   r_index = (const int*)d_in[1];
    const float* theta   = (const float*)d_in[2];
    const float* lnw     = (const float*)d_in[3];

    float* x_reg = (float*)d_out;
    float* L     = (float*)d_out + (size_t)NB * INP;

    float* partial = (float*)d_ws;            // 8*4096 floats = 128 KB
    float* s       = partial + NB * NBLK1;    // 8 floats

    dim3 grid1(NBLK1, NB);
    k_sample<<<grid1, 256, 0, stream>>>(x, r_index, theta, lnw, x_reg, partial);
    k_reduce<<<NB, 256, 0, stream>>>(partial, s);
    k_outer<<<INP / 4 / 256, 256, 0, stream>>>(lnw, s, L);
}

// Round 12
// 39.530 us; speedup vs baseline: 3.7092x; 1.1149x over previous
//
#include <hip/hip_runtime.h>

#define INP (128*128*64)   // 1048576
#define NB 8
#define NBLK2 2048         // k_sample blocks per batch: (INP/2)/256

typedef __attribute__((ext_vector_type(4))) float f32x4;
typedef __attribute__((ext_vector_type(2))) float f32x2;
typedef int v4i __attribute__((ext_vector_type(4)));

#if __has_builtin(__builtin_amdgcn_make_buffer_rsrc) && __has_builtin(__builtin_amdgcn_raw_buffer_load_b32)
#define RSRC_T __amdgpu_buffer_rsrc_t
__device__ __forceinline__ RSRC_T make_rsrc(const float* p) {
    return __builtin_amdgcn_make_buffer_rsrc((void*)p, (short)0, INP * 4, 0x00020000);
}
__device__ __forceinline__ float bload(RSRC_T r, int boff) {
    return __builtin_bit_cast(float, __builtin_amdgcn_raw_buffer_load_b32(r, boff, 0, 0));
}
#else
#define RSRC_T v4i
__device__ __forceinline__ RSRC_T make_rsrc(const float* p) {
    union { const float* p; unsigned u[2]; } pun; pun.p = p;
    RSRC_T r;
    r.x = (int)pun.u[0]; r.y = (int)pun.u[1]; r.z = INP * 4; r.w = 0x00020000;
    return r;
}
__device__ __forceinline__ float bload(RSRC_T r, int boff) {
    return __builtin_amdgcn_raw_buffer_load_f32(r, boff, 0, 0);
}
#endif

#if __has_builtin(__builtin_amdgcn_raw_buffer_load_b64)
__device__ __forceinline__ f32x2 bload2(RSRC_T r, int boff) {
    return __builtin_bit_cast(f32x2, __builtin_amdgcn_raw_buffer_load_b64(r, boff, 0, 0));
}
#else
__device__ __forceinline__ f32x2 bload2(RSRC_T r, int boff) {
    f32x2 v; v.x = bload(r, boff); v.y = bload(r, boff + 4); return v;
}
#endif

__device__ __forceinline__ float wave_reduce(float v) {
    #pragma unroll
    for (int off = 32; off > 0; off >>= 1) v += __shfl_down(v, off, 64);
    return v;
}

// One trilinear sample at voxel coords (ix,iy,iz). R10-proven gather:
// each (z,y) row's two x-corners via ONE 8-byte load at xp=clamp(x0,0,62)
// (row-aligned, always in-bounds); edges via 2 shared compares + cndmask:
//   v*00 = (x0>=63) ? pair.y : pair.x   (x0=63: wx1=0, need x[63]=pair.y)
//   v*01 = (x0<0)   ? pair.x : pair.y   (x0=-1: wx0=0, need x[0]=pair.x)
// All other OOB: both wx zeroed. 4 VMEM instrs/sample. Do NOT use unclamped
// offsets with SRSRC (R3/R7: imm-folding breaks the >=33-bit bounds check).
__device__ __forceinline__ float sample1(RSRC_T r, float ix, float iy, float iz) {
    const float fx = floorf(ix), fy = floorf(iy), fz = floorf(iz);
    const int x0 = (int)fx, y0 = (int)fy, z0 = (int)fz;
    const int x1 = x0 + 1,  y1 = y0 + 1,  z1 = z0 + 1;

    float wx1 = ix - fx, wx0 = 1.f - wx1;
    float wy1 = iy - fy, wy0 = 1.f - wy1;
    float wz1 = iz - fz, wz0 = 1.f - wz1;
    wx0 = ((unsigned)x0 < 64u)  ? wx0 : 0.f;
    wx1 = ((unsigned)x1 < 64u)  ? wx1 : 0.f;
    wy0 = ((unsigned)y0 < 128u) ? wy0 : 0.f;
    wy1 = ((unsigned)y1 < 128u) ? wy1 : 0.f;
    wz0 = ((unsigned)z0 < 128u) ? wz0 : 0.f;
    wz1 = ((unsigned)z1 < 128u) ? wz1 : 0.f;

    const int yc0 = min(max(y0, 0), 127), yc1 = min(max(y1, 0), 127);
    const int zc0 = min(max(z0, 0), 127), zc1 = min(max(z1, 0), 127);
    const int xpb = min(max(x0, 0), 62) << 2;
    const int yb0 = (yc0 << 8) + xpb, yb1 = (yc1 << 8) + xpb;
    const int zb0 = zc0 << 15,        zb1 = zc1 << 15;

    const f32x2 p00 = bload2(r, zb0 + yb0);
    const f32x2 p01 = bload2(r, zb0 + yb1);
    const f32x2 p10 = bload2(r, zb1 + yb0);
    const f32x2 p11 = bload2(r, zb1 + yb1);

    const bool hi = (x0 >= 63);
    const bool lo = (x0 < 0);
    const float v000 = hi ? p00.y : p00.x, v001 = lo ? p00.x : p00.y;
    const float v010 = hi ? p01.y : p01.x, v011 = lo ? p01.x : p01.y;
    const float v100 = hi ? p10.y : p10.x, v101 = lo ? p10.x : p10.y;
    const float v110 = hi ? p11.y : p11.x, v111 = lo ? p11.x : p11.y;

    const float bx00 = fmaf(wx1, v001, wx0 * v000);
    const float bx01 = fmaf(wx1, v011, wx0 * v010);
    const float bx10 = fmaf(wx1, v101, wx0 * v100);
    const float bx11 = fmaf(wx1, v111, wx0 * v110);
    const float by0  = fmaf(wy1, bx01, wy0 * bx00);
    const float by1  = fmaf(wy1, bx11, wy0 * bx10);
    return fmaf(wz1, by1, wz0 * by0);
}

// ---------------------------------------------------------------------------
// K1: one thread = TWO x-adjacent voxels (2*i2, 2*i2+1) of one batch, same
// (h,d). Matvec+unnorm computed once; voxel 1 coords advance by constants
// (d(ix)/dw = t0, d(iy)/dw = 2*t4, d(iz)/dw = 2*t8). Lanes stay consecutive
// in w (R9 lesson: gather line-footprint per wave must stay minimal).
// f32x2 NT store + f32x2 lnw load. R5-proven LDS-combined partial tail.
// ---------------------------------------------------------------------------
__global__ __launch_bounds__(256) void k_sample(
    const float* __restrict__ x, const int* __restrict__ r_index,
    const float* __restrict__ theta, const float* __restrict__ lnw,
    float* __restrict__ x_reg, float* __restrict__ partial)
{
    const int b  = blockIdx.y;
    const int i2 = blockIdx.x * 256 + threadIdx.x;   // pair index
    const int w0 = (i2 & 31) << 1;                   // w of voxel 0
    const int h  = (i2 >> 5) & 127;
    const int d  = i2 >> 12;

    const f32x2 w2 = ((const f32x2*)lnw)[i2];        // issue early

    const float xs = fmaf((float)w0, 1.f/32.f, 1.f/64.f  - 1.f);
    const float ys = fmaf((float)h,  1.f/64.f, 1.f/128.f - 1.f);
    const float zs = fmaf((float)d,  1.f/64.f, 1.f/128.f - 1.f);

    const float* __restrict__ t = theta + r_index[b] * 12;   // uniform
    const float gx = fmaf(t[0], xs, fmaf(t[1], ys, fmaf(t[2],  zs, t[3])));
    const float gy = fmaf(t[4], xs, fmaf(t[5], ys, fmaf(t[6],  zs, t[7])));
    const float gz = fmaf(t[8], xs, fmaf(t[9], ys, fmaf(t[10], zs, t[11])));
    const float ix0 = fmaf(gx, 32.f, 31.5f);
    const float iy0 = fmaf(gy, 64.f, 63.5f);
    const float iz0 = fmaf(gz, 64.f, 63.5f);

    const RSRC_T r = make_rsrc(x + (size_t)b * INP);
    const float o0 = sample1(r, ix0, iy0, iz0);
    const float o1 = sample1(r, ix0 + t[0], iy0 + 2.f*t[4], iz0 + 2.f*t[8]);

    f32x2 o; o.x = o0; o.y = o1;
    __builtin_nontemporal_store(o, (f32x2*)(x_reg + (size_t)b * INP) + i2);

    // R5-proven tail: wave shfl reduce -> LDS combine -> ONE store per block
    float acc = fmaf(o1, w2.y, o0 * w2.x);
    acc = wave_reduce(acc);
    __shared__ float sm[4];
    const int lane = threadIdx.x & 63;
    const int wv   = threadIdx.x >> 6;
    if (lane == 0) sm[wv] = acc;
    __syncthreads();
    if (threadIdx.x == 0)
        partial[b * NBLK2 + blockIdx.x] = sm[0] + sm[1] + sm[2] + sm[3];
}

// ---------------------------------------------------------------------------
// K2: reduce (8, NBLK2) partials -> s[8]
// ---------------------------------------------------------------------------
__global__ __launch_bounds__(256) void k_reduce(
    const float* __restrict__ partial, float* __restrict__ s)
{
    const int b = blockIdx.x;
    float v = 0.f;
    for (int t = threadIdx.x; t < NBLK2; t += 256) v += partial[b * NBLK2 + t];
    __shared__ float sm[4];
    v = wave_reduce(v);
    if ((threadIdx.x & 63) == 0) sm[threadIdx.x >> 6] = v;
    __syncthreads();
    if (threadIdx.x == 0) s[b] = sm[0] + sm[1] + sm[2] + sm[3];
}

// ---------------------------------------------------------------------------
// K3: L[b,i] = s[b] * lnw[i], f32x4, NT stores
// ---------------------------------------------------------------------------
__global__ __launch_bounds__(256) void k_outer(
    const float* __restrict__ lnw, const float* __restrict__ s,
    float* __restrict__ L)
{
    const int i = blockIdx.x * 256 + threadIdx.x;
    const f32x4 w4 = ((const f32x4*)lnw)[i];
    #pragma unroll
    for (int b = 0; b < NB; ++b) {
        const float sb = s[b];
        f32x4 o = sb * w4;
        __builtin_nontemporal_store(o, (f32x4*)(L + (size_t)b * INP) + i);
    }
}

extern "C" void kernel_launch(void* const* d_in, const int* in_sizes, int n_in,
                              void* d_out, int out_size, void* d_ws, size_t ws_size,
                              hipStream_t stream) {
    const float* x       = (const float*)d_in[0];
    const int*   r_index = (const int*)d_in[1];
    const float* theta   = (const float*)d_in[2];
    const float* lnw     = (const float*)d_in[3];

    float* x_reg = (float*)d_out;
    float* L     = (float*)d_out + (size_t)NB * INP;

    float* partial = (float*)d_ws;            // 8*2048 floats = 64 KB
    float* s       = partial + NB * NBLK2;    // 8 floats

    dim3 grid1(NBLK2, NB);
    k_sample<<<grid1, 256, 0, stream>>>(x, r_index, theta, lnw, x_reg, partial);
    k_reduce<<<NB, 256, 0, stream>>>(partial, s);
    k_outer<<<INP / 4 / 256, 256, 0, stream>>>(lnw, s, L);
}

// Round 13
// 33.963 us; speedup vs baseline: 4.3173x; 1.1639x over previous
//
#include <hip/hip_runtime.h>

#define INP (128*128*64)   // 1048576
#define NB 8
#define NBLK2 2048         // k_sample blocks per batch: (INP/2)/256

typedef __attribute__((ext_vector_type(4))) float f32x4;
typedef __attribute__((ext_vector_type(2))) float f32x2;
typedef int v4i __attribute__((ext_vector_type(4)));

#if __has_builtin(__builtin_amdgcn_make_buffer_rsrc) && __has_builtin(__builtin_amdgcn_raw_buffer_load_b32)
#define RSRC_T __amdgpu_buffer_rsrc_t
__device__ __forceinline__ RSRC_T make_rsrc(const float* p) {
    return __builtin_amdgcn_make_buffer_rsrc((void*)p, (short)0, INP * 4, 0x00020000);
}
__device__ __forceinline__ float bload(RSRC_T r, int boff) {
    return __builtin_bit_cast(float, __builtin_amdgcn_raw_buffer_load_b32(r, boff, 0, 0));
}
#else
#define RSRC_T v4i
__device__ __forceinline__ RSRC_T make_rsrc(const float* p) {
    union { const float* p; unsigned u[2]; } pun; pun.p = p;
    RSRC_T r;
    r.x = (int)pun.u[0]; r.y = (int)pun.u[1]; r.z = INP * 4; r.w = 0x00020000;
    return r;
}
__device__ __forceinline__ float bload(RSRC_T r, int boff) {
    return __builtin_amdgcn_raw_buffer_load_f32(r, boff, 0, 0);
}
#endif

#if __has_builtin(__builtin_amdgcn_raw_buffer_load_b64)
__device__ __forceinline__ f32x2 bload2(RSRC_T r, int boff) {
    return __builtin_bit_cast(f32x2, __builtin_amdgcn_raw_buffer_load_b64(r, boff, 0, 0));
}
#else
__device__ __forceinline__ f32x2 bload2(RSRC_T r, int boff) {
    f32x2 v; v.x = bload(r, boff); v.y = bload(r, boff + 4); return v;
}
#endif

__device__ __forceinline__ float wave_reduce(float v) {
    #pragma unroll
    for (int off = 32; off > 0; off >>= 1) v += __shfl_down(v, off, 64);
    return v;
}

// Per-sample prep: 4 clamped row-base offsets (always in-bounds; R3/R7 lesson:
// never rely on SRSRC OOB with negative voffset + folded imm) and 6 final
// weights. x-edge cases resolved in the WEIGHTS (wa on pair.x, wb on pair.y):
//   interior: (wa,wb) = (wx0, wx1)
//   x0=63 (xp=62): contribution is wx0*x[63] = wx0*pair.y -> (0, wx0)
//   x0=-1 (xp=0):  contribution is wx1*x[0]  = wx1*pair.x -> (wx1, 0)
//   |x0| further out: both zeroed. Audited exhaustively vs zeroing table.
struct Prep {
    int o[4];
    float wa, wb, wy0, wy1, wz0, wz1;
};

__device__ __forceinline__ Prep prep_s(float ix, float iy, float iz) {
    const float fx = floorf(ix), fy = floorf(iy), fz = floorf(iz);
    const int x0 = (int)fx, y0 = (int)fy, z0 = (int)fz;
    const int x1 = x0 + 1,  y1 = y0 + 1,  z1 = z0 + 1;

    const float wx1 = ix - fx, wx0 = 1.f - wx1;
    Prep p;
    p.wy1 = iy - fy; p.wy0 = 1.f - p.wy1;
    p.wz1 = iz - fz; p.wz0 = 1.f - p.wz1;
    p.wy0 = ((unsigned)y0 < 128u) ? p.wy0 : 0.f;
    p.wy1 = ((unsigned)y1 < 128u) ? p.wy1 : 0.f;
    p.wz0 = ((unsigned)z0 < 128u) ? p.wz0 : 0.f;
    p.wz1 = ((unsigned)z1 < 128u) ? p.wz1 : 0.f;

    const float wx0z = ((unsigned)x0 < 64u) ? wx0 : 0.f;
    const float wx1z = ((unsigned)x1 < 64u) ? wx1 : 0.f;
    const bool hi = (x0 >= 63);
    const bool lo = (x0 < 0);
    p.wa = lo ? wx1z : (hi ? 0.f : wx0z);
    p.wb = hi ? wx0z : (lo ? 0.f : wx1z);

    const int yc0 = min(max(y0, 0), 127), yc1 = min(max(y1, 0), 127);
    const int zc0 = min(max(z0, 0), 127), zc1 = min(max(z1, 0), 127);
    const int xpb = min(max(x0, 0), 62) << 2;
    const int yb0 = (yc0 << 8) + xpb, yb1 = (yc1 << 8) + xpb;
    const int zb0 = zc0 << 15,        zb1 = zc1 << 15;
    p.o[0] = zb0 + yb0; p.o[1] = zb0 + yb1;
    p.o[2] = zb1 + yb0; p.o[3] = zb1 + yb1;
    return p;
}

__device__ __forceinline__ float blend_s(const Prep& p, const f32x2 v[4]) {
    const float bx00 = fmaf(p.wb, v[0].y, p.wa * v[0].x);
    const float bx01 = fmaf(p.wb, v[1].y, p.wa * v[1].x);
    const float bx10 = fmaf(p.wb, v[2].y, p.wa * v[2].x);
    const float bx11 = fmaf(p.wb, v[3].y, p.wa * v[3].x);
    const float by0  = fmaf(p.wy1, bx01, p.wy0 * bx00);
    const float by1  = fmaf(p.wy1, bx11, p.wy0 * bx10);
    return fmaf(p.wz1, by1, p.wz0 * by0);
}

// ---------------------------------------------------------------------------
// K1: one thread = TWO x-adjacent voxels (R12-proven). Matvec+unnorm once;
// voxel 1 advances by (t0, 2*t4, 2*t8). Both samples' offsets computed, then
// all 8 pair-loads issued, then both blends. f32x2 NT store + f32x2 lnw load.
// R5-proven LDS-combined partial tail (one store per block).
// ---------------------------------------------------------------------------
__global__ __launch_bounds__(256) void k_sample(
    const float* __restrict__ x, const int* __restrict__ r_index,
    const float* __restrict__ theta, const float* __restrict__ lnw,
    float* __restrict__ x_reg, float* __restrict__ partial)
{
    const int b  = blockIdx.y;
    const int i2 = blockIdx.x * 256 + threadIdx.x;   // pair index
    const int w0 = (i2 & 31) << 1;                   // w of voxel 0
    const int h  = (i2 >> 5) & 127;
    const int d  = i2 >> 12;

    const f32x2 w2 = ((const f32x2*)lnw)[i2];        // issue early

    const float xs = fmaf((float)w0, 1.f/32.f, 1.f/64.f  - 1.f);
    const float ys = fmaf((float)h,  1.f/64.f, 1.f/128.f - 1.f);
    const float zs = fmaf((float)d,  1.f/64.f, 1.f/128.f - 1.f);

    const float* __restrict__ t = theta + r_index[b] * 12;   // uniform
    const float gx = fmaf(t[0], xs, fmaf(t[1], ys, fmaf(t[2],  zs, t[3])));
    const float gy = fmaf(t[4], xs, fmaf(t[5], ys, fmaf(t[6],  zs, t[7])));
    const float gz = fmaf(t[8], xs, fmaf(t[9], ys, fmaf(t[10], zs, t[11])));
    const float ix0 = fmaf(gx, 32.f, 31.5f);
    const float iy0 = fmaf(gy, 64.f, 63.5f);
    const float iz0 = fmaf(gz, 64.f, 63.5f);

    const RSRC_T r = make_rsrc(x + (size_t)b * INP);

    const Prep p0 = prep_s(ix0, iy0, iz0);
    const Prep p1 = prep_s(ix0 + t[0], iy0 + 2.f*t[4], iz0 + 2.f*t[8]);

    f32x2 v0[4], v1[4];
    #pragma unroll
    for (int j = 0; j < 4; ++j) v0[j] = bload2(r, p0.o[j]);
    #pragma unroll
    for (int j = 0; j < 4; ++j) v1[j] = bload2(r, p1.o[j]);

    const float o0 = blend_s(p0, v0);
    const float o1 = blend_s(p1, v1);

    f32x2 o; o.x = o0; o.y = o1;
    __builtin_nontemporal_store(o, (f32x2*)(x_reg + (size_t)b * INP) + i2);

    // R5-proven tail: wave shfl reduce -> LDS combine -> ONE store per block
    float acc = fmaf(o1, w2.y, o0 * w2.x);
    acc = wave_reduce(acc);
    __shared__ float sm[4];
    if ((threadIdx.x & 63) == 0) sm[threadIdx.x >> 6] = acc;
    __syncthreads();
    if (threadIdx.x == 0)
        partial[b * NBLK2 + blockIdx.x] = sm[0] + sm[1] + sm[2] + sm[3];
}

// ---------------------------------------------------------------------------
// K2 (fused reduce+outer): grid (128 chunks, 8 batches). Each block
// redundantly reduces its batch's 2048 partials (2 f32x4 loads/thread,
// deterministic fixed tree), then writes its 8192-float chunk of
// L[b] = s_b * lnw. Saves the separate k_reduce launch + bubble.
// ---------------------------------------------------------------------------
__global__ __launch_bounds__(256) void k_outer(
    const float* __restrict__ lnw, const float* __restrict__ partial,
    float* __restrict__ L)
{
    const int b   = blockIdx.y;
    const int tid = threadIdx.x;

    const f32x4* p4 = (const f32x4*)(partial + b * NBLK2);   // 512 f32x4
    const f32x4 a0 = p4[tid];
    const f32x4 a1 = p4[tid + 256];
    float v = (a0.x + a0.y) + (a0.z + a0.w) + (a1.x + a1.y) + (a1.z + a1.w);
    v = wave_reduce(v);
    __shared__ float sm[4];
    __shared__ float smt;
    if ((tid & 63) == 0) sm[tid >> 6] = v;
    __syncthreads();
    if (tid == 0) smt = (sm[0] + sm[1]) + (sm[2] + sm[3]);
    __syncthreads();
    const float sb = smt;

    const int base = blockIdx.x * 2048 + tid;    // f32x4 units within batch
    const f32x4* w4p = (const f32x4*)lnw;
    f32x4* L4 = (f32x4*)L + (size_t)b * (INP / 4);
    #pragma unroll
    for (int k = 0; k < 8; ++k) {
        const f32x4 w4 = w4p[base + k * 256];
        __builtin_nontemporal_store(sb * w4, L4 + base + k * 256);
    }
}

extern "C" void kernel_launch(void* const* d_in, const int* in_sizes, int n_in,
                              void* d_out, int out_size, void* d_ws, size_t ws_size,
                              hipStream_t stream) {
    const float* x       = (const float*)d_in[0];
    const int*   r_index = (const int*)d_in[1];
    const float* theta   = (const float*)d_in[2];
    const float* lnw     = (const float*)d_in[3];

    float* x_reg = (float*)d_out;
    float* L     = (float*)d_out + (size_t)NB * INP;

    float* partial = (float*)d_ws;            // 8*2048 floats = 64 KB

    dim3 grid1(NBLK2, NB);
    k_sample<<<grid1, 256, 0, stream>>>(x, r_index, theta, lnw, x_reg, partial);
    dim3 grid2(128, NB);
    k_outer<<<grid2, 256, 0, stream>>>(lnw, partial, L);
}